// Round 2
// baseline (231.332 us; speedup 1.0000x reference)
//
#include <hip/hip_runtime.h>
#include <math.h>

#define N_TOTAL 131072
#define BB 8
#define KK 20
#define CC 96
#define LOG2E 1.4426950408889634f

// ---------------- Kernel A: per-block segment (max, sum) partials ----------------
// grid GA blocks x 320 threads; chunk = N/GA contiguous points.
// thread t: k = t%20, sub = t/20 (16 subs); points p = base + sub + 16*i.
#define GA 512
#define CHUNKA (N_TOTAL / GA)   // 256
#define SUBS 16
#define THRA 320

__global__ __launch_bounds__(THRA) void seg_ms_kernel(
    const float* __restrict__ probs, const int* __restrict__ bidx,
    float* __restrict__ mPart, float* __restrict__ sPart) {
  __shared__ float lm[SUBS][BB][KK];
  __shared__ float ls[SUBS][BB][KK];
  const int t = threadIdx.x;
  const int k = t % KK, sub = t / KK;
  for (int i = t; i < SUBS * BB * KK; i += THRA) {
    ((float*)lm)[i] = -1e30f;
    ((float*)ls)[i] = 0.f;
  }
  __syncthreads();
  const int base = blockIdx.x * CHUNKA;
  float m = -1e30f, s = 0.f;
  int cb = bidx[base + sub];
  #pragma unroll 4
  for (int i = 0; i < CHUNKA / SUBS; ++i) {
    const int p = base + sub + i * SUBS;
    const float q = probs[(size_t)p * KK + k] * LOG2E;
    const int b = bidx[p];
    if (b != cb) {           // sorted -> each b visited at most once per thread
      lm[sub][cb][k] = m; ls[sub][cb][k] = s;
      m = -1e30f; s = 0.f; cb = b;
    }
    const float mn = fmaxf(m, q);
    s = s * exp2f(m - mn) + exp2f(q - mn);
    m = mn;
  }
  lm[sub][cb][k] = m; ls[sub][cb][k] = s;
  __syncthreads();
  if (t < BB * KK) {
    const int b = t / KK, kk = t % KK;
    float M = -1e30f, S = 0.f;
    #pragma unroll
    for (int u = 0; u < SUBS; ++u) {
      const float m2 = lm[u][b][kk], s2 = ls[u][b][kk];
      const float Mn = fmaxf(M, m2);
      S = S * exp2f(M - Mn) + s2 * exp2f(m2 - Mn);
      M = Mn;
    }
    mPart[blockIdx.x * (BB * KK) + t] = M;
    sPart[blockIdx.x * (BB * KK) + t] = S;
  }
}

// ---------------- Kernel B: reduce partials -> off[b][k] = M + log2(S) ----------------
#define THRB 640
__global__ __launch_bounds__(THRB) void seg_off_kernel(
    const float* __restrict__ mPart, const float* __restrict__ sPart,
    float* __restrict__ off) {
  __shared__ float lM[4][BB * KK];
  __shared__ float lS[4][BB * KK];
  const int t = threadIdx.x;
  const int cell = t % (BB * KK), qa = t / (BB * KK);
  const int G4 = GA / 4;
  float M = -1e30f;
  #pragma unroll 4
  for (int g = qa * G4; g < qa * G4 + G4; ++g)
    M = fmaxf(M, mPart[g * (BB * KK) + cell]);
  lM[qa][cell] = M;
  __syncthreads();
  M = fmaxf(fmaxf(lM[0][cell], lM[1][cell]), fmaxf(lM[2][cell], lM[3][cell]));
  float S = 0.f;
  #pragma unroll 4
  for (int g = qa * G4; g < qa * G4 + G4; ++g)
    S += sPart[g * (BB * KK) + cell] * exp2f(mPart[g * (BB * KK) + cell] - M);
  lS[qa][cell] = S;
  __syncthreads();
  if (t < BB * KK) {
    const float St = lS[0][cell] + lS[1][cell] + lS[2][cell] + lS[3][cell];
    off[cell] = M + log2f(St);
  }
}

// ---------------- Kernel C: weighted aggregation ----------------
// grid GC x 256; chunk = 128 contiguous points per block.
// active threads 240: pslot = t/60 (4 points per pass), r = t%60,
// kg = r/12 (4 k's), cg = r%12 (8 c's). acc[4][8] in registers.
// NOTE: all __syncthreads() are at top level, executed by ALL 256 threads
// (a prior version early-returned inactive threads -> intra-wave divergent
// barrier -> hang).
#define GC 1024
#define CHUNKC (N_TOTAL / GC)   // 128
#define PSL 4
#define TPP 60
#define ACTIVE (PSL * TPP)      // 240

__global__ __launch_bounds__(256) void gather_kernel(
    const float* __restrict__ feats, const float* __restrict__ probs,
    const int* __restrict__ bidx, const float* __restrict__ off,
    float* __restrict__ out) {
  __shared__ float loff[BB * KK];
  __shared__ float lfl[PSL - 1][TPP][32];
  const int t = threadIdx.x;
  if (t < BB * KK) loff[t] = off[t];
  __syncthreads();

  const bool active = t < ACTIVE;
  const int pslot = t / TPP, r = t % TPP;   // pslot in 0..3 for active threads
  const int kg = r / 12, cg = r % 12;
  const int base = blockIdx.x * CHUNKC;
  const bool multi = bidx[base] != bidx[base + CHUNKC - 1];  // block-uniform

  float acc[4][8];
  #pragma unroll
  for (int i = 0; i < 4; ++i)
    #pragma unroll
    for (int j = 0; j < 8; ++j) acc[i][j] = 0.f;
  int cb = 0;

  if (active) {
    int n = base + pslot;
    cb = bidx[n];
    float offr[4];
    #pragma unroll
    for (int i = 0; i < 4; ++i) offr[i] = loff[cb * KK + kg * 4 + i];

    const float* pp = probs + (size_t)n * KK + kg * 4;
    const float* fp = feats + (size_t)n * CC + cg * 8;
    float4 pv = *(const float4*)pp;
    float4 f0 = *(const float4*)fp;
    float4 f1 = *(const float4*)(fp + 4);
    int b = cb;

    const int PASSES = CHUNKC / PSL;  // 32
    for (int pass = 0; pass < PASSES; ++pass) {
      const int adv = (pass + 1 < PASSES) ? PSL : 0;
      const float* pp2 = pp + (size_t)adv * KK;
      const float* fp2 = fp + (size_t)adv * CC;
      // 1-deep pipeline: issue next loads before computing current
      const float4 pvn = *(const float4*)pp2;
      const float4 f0n = *(const float4*)fp2;
      const float4 f1n = *(const float4*)(fp2 + 4);
      const int bn = bidx[n + adv];

      if (multi && b != cb) {   // rare slow path (batch boundary inside chunk)
        #pragma unroll
        for (int i = 0; i < 4; ++i)
          #pragma unroll
          for (int j = 0; j < 8; ++j) {
            atomicAdd(out + cb * (KK * CC) + (kg * 4 + i) * CC + cg * 8 + j, acc[i][j]);
            acc[i][j] = 0.f;
          }
        cb = b;
        #pragma unroll
        for (int i = 0; i < 4; ++i) offr[i] = loff[cb * KK + kg * 4 + i];
      }

      float wr[4];
      wr[0] = exp2f(fmaf(pv.x, LOG2E, -offr[0]));
      wr[1] = exp2f(fmaf(pv.y, LOG2E, -offr[1]));
      wr[2] = exp2f(fmaf(pv.z, LOG2E, -offr[2]));
      wr[3] = exp2f(fmaf(pv.w, LOG2E, -offr[3]));
      const float fr[8] = {f0.x, f0.y, f0.z, f0.w, f1.x, f1.y, f1.z, f1.w};
      #pragma unroll
      for (int i = 0; i < 4; ++i)
        #pragma unroll
        for (int j = 0; j < 8; ++j)
          acc[i][j] = fmaf(wr[i], fr[j], acc[i][j]);

      pv = pvn; f0 = f0n; f1 = f1n; b = bn;
      pp = pp2; fp = fp2; n += adv;
    }
  }

  // ---- flush (uniform barrier structure) ----
  if (active && !multi && pslot > 0) {
    #pragma unroll
    for (int i = 0; i < 4; ++i)
      #pragma unroll
      for (int j = 0; j < 8; ++j)
        lfl[pslot - 1][r][i * 8 + j] = acc[i][j];
  }
  __syncthreads();
  if (active) {
    if (multi) {
      #pragma unroll
      for (int i = 0; i < 4; ++i)
        #pragma unroll
        for (int j = 0; j < 8; ++j)
          atomicAdd(out + cb * (KK * CC) + (kg * 4 + i) * CC + cg * 8 + j, acc[i][j]);
    } else if (pslot == 0) {
      #pragma unroll
      for (int i = 0; i < 4; ++i)
        #pragma unroll
        for (int j = 0; j < 8; ++j) {
          const float v = acc[i][j] + lfl[0][r][i * 8 + j] +
                          lfl[1][r][i * 8 + j] + lfl[2][r][i * 8 + j];
          atomicAdd(out + cb * (KK * CC) + (kg * 4 + i) * CC + cg * 8 + j, v);
        }
    }
  }
}

extern "C" void kernel_launch(void* const* d_in, const int* in_sizes, int n_in,
                              void* d_out, int out_size, void* d_ws, size_t ws_size,
                              hipStream_t stream) {
  const float* feats = (const float*)d_in[0];
  const float* probs = (const float*)d_in[1];
  const int* bidx = (const int*)d_in[3];
  float* out = (float*)d_out;

  float* mPart = (float*)d_ws;                 // [GA][160]
  float* sPart = mPart + (size_t)GA * BB * KK; // [GA][160]
  float* off   = sPart + (size_t)GA * BB * KK; // [160]

  hipMemsetAsync(d_out, 0, (size_t)BB * KK * CC * sizeof(float), stream);
  seg_ms_kernel<<<GA, THRA, 0, stream>>>(probs, bidx, mPart, sPart);
  seg_off_kernel<<<1, THRB, 0, stream>>>(mPart, sPart, off);
  gather_kernel<<<GC, 256, 0, stream>>>(feats, probs, bidx, off, out);
}